// Round 5
// baseline (204.410 us; speedup 1.0000x reference)
//
#include <hip/hip_runtime.h>
#include <hip/hip_bf16.h>

#define IN_F  4096
#define OUT_F 11008
#define SEQ   512
#define NOUT  4096

#define BM 128
#define BN 64
#define BK 32
#define NT   (IN_F / BK)        // 128 K-phases
#define NBLK (OUT_F / BN)       // 172
#define MBLK (SEQ / BM)         // 4
#define NWG  (NBLK * MBLK)      // 688 = 8 * 86 -> bijective XCD swizzle

#define HSLOTS 8192             // dedup hash table (load factor 0.5)

// ws layout: [0,4MB) X as bf16; dedup'd outlier table; hash table
#define WS_TAB_I ((size_t)SEQ * IN_F * 2)
#define WS_TAB_F (WS_TAB_I + (size_t)NOUT * 4)
#define WS_HKEY  (WS_TAB_F + (size_t)NOUT * 4)
#define WS_HVAL  (WS_HKEY + (size_t)HSLOTS * 4)

typedef __attribute__((ext_vector_type(8))) short bf16x8;
typedef __attribute__((ext_vector_type(4))) float f32x4;
typedef __attribute__((ext_vector_type(4))) int   int4v;
typedef __attribute__((ext_vector_type(4))) float float4v;

union Pack8 { bf16x8 v; __hip_bfloat16 h[8]; };

__device__ __forceinline__ unsigned hslot(int key) {
    return ((unsigned)key * 2654435761u) & (HSLOTS - 1);
}

// ---- prep 1: X fp32 -> bf16 (vectorized) ----
__global__ __launch_bounds__(256) void prep_x(const float* __restrict__ X,
                                              __hip_bfloat16* __restrict__ Xb) {
    const int i = (blockIdx.x * 256 + threadIdx.x) * 8;
    float4v x0 = *(const float4v*)(X + i);
    float4v x1 = *(const float4v*)(X + i + 4);
    Pack8 p;
    #pragma unroll
    for (int j = 0; j < 4; ++j) {
        p.h[j]     = __float2bfloat16(x0[j]);
        p.h[4 + j] = __float2bfloat16(x1[j]);
    }
    *(bf16x8*)(Xb + i) = p.v;
}

// ---- prep 2a: insert outliers, last-wins via atomicMax on entry index ----
__global__ __launch_bounds__(256) void prep_hins(const int* __restrict__ oidx,
                                                 int* __restrict__ hkey,
                                                 int* __restrict__ hval) {
    const int j = blockIdx.x * 256 + threadIdx.x;
    const int key = oidx[2 * j] * IN_F + oidx[2 * j + 1];
    unsigned s = hslot(key);
    while (true) {
        const int prev = atomicCAS(&hkey[s], -1, key);
        if (prev == -1 || prev == key) break;
        s = (s + 1) & (HSLOTS - 1);
    }
    atomicMax(&hval[s], j);
}

// ---- prep 2b: resolve dups + delta table (delta vs EXACT q*scale, since the
// GEMM now contributes scale[o] * (exact q) * bf16(x)) ----
__global__ __launch_bounds__(256) void prep_tab(
    const int* __restrict__ oidx, const float* __restrict__ outv,
    const int* __restrict__ Q, const float* __restrict__ scale,
    const int* __restrict__ hkey, const int* __restrict__ hval,
    int* __restrict__ tabi, float* __restrict__ tabf) {
    const int j = blockIdx.x * 256 + threadIdx.x;
    const int r = oidx[2 * j], c = oidx[2 * j + 1];
    const int key = r * IN_F + c;
    unsigned s = hslot(key);
    while (hkey[s] != key) s = (s + 1) & (HSLOTS - 1);
    if (hval[s] != j) { tabi[j] = -1; tabf[j] = 0.f; return; }   // later dup wins
    tabi[j] = (r << 16) | c;
    tabf[j] = outv[j] - (float)Q[(size_t)r * IN_F + c] * scale[r];
}

// ---- main: unscaled int-as-bf16 GEMM, triple-buffered A (2-ahead gload_lds),
// dbuf B (reg-staged 2-ahead), counted vmcnt, scale+bias+outliers in epilogue.
__global__ __launch_bounds__(256) void qgemm4(
    const __hip_bfloat16* __restrict__ Xb,
    const int*   __restrict__ Q,
    const float* __restrict__ scale,
    const float* __restrict__ bias,
    const int*   __restrict__ tabi,
    const float* __restrict__ tabf,
    float* __restrict__ out)
{
    __shared__ __hip_bfloat16 sA[3][BM * BK];   // 24 KB, chunk-swizzled
    __shared__ __hip_bfloat16 sB[2][BN * BK];   // 8 KB, chunk-swizzled
    __shared__ int   list[256];
    __shared__ float ldel[256];
    __shared__ int   lcount;

    const int tid  = threadIdx.x;
    const int wave = tid >> 6;
    const int lane = tid & 63;

    // XCD-aware swizzle; 4 consecutive tiles share one Q panel (L2 reuse).
    const int lin = blockIdx.x;
    const int t0  = (lin & 7) * (NWG / 8) + (lin >> 3);
    const int col0 = (t0 >> 2) * BN;
    const int row0 = (t0 & 3) * BM;

    const int wm = (wave >> 1) * 64;
    const int wn = (wave & 1) * 32;
    const int fr = lane & 15;         // fragment row within 16
    const int fc = lane >> 4;         // k-chunk 0..3 (8 bf16 each)

    f32x4 acc[4][2] = {};

    // A staging: 8KB/phase via 2 gload_lds per thread. Call i covers rows
    // wave*32+i*16..+15; lane l -> row_off l>>2, chunk slot l&3. Source is
    // chunk-XOR-preswizzled: slot c of row r holds logical chunk c^(r&3).
    const int arow_off = lane >> 2;                    // 0..15
    const int asw = ((lane & 3) ^ (arow_off & 3)) * 8; // source elem offset
    const __hip_bfloat16* asrc =
        Xb + (size_t)(row0 + wave * 32 + arow_off) * IN_F + asw;
    auto issueA = [&](int buf, int k0) {
        #pragma unroll
        for (int i = 0; i < 2; ++i)
            __builtin_amdgcn_global_load_lds(
                (const __attribute__((address_space(1))) void*)(asrc + (size_t)i * 16 * IN_F + k0),
                (__attribute__((address_space(3))) void*)&sA[buf][(wave * 32 + i * 16) * BK],
                16, 0, 0);
    };

    // B staging: thread covers Q row srb (4 thr/row), 8 ints at elem (tid&3)*8;
    // convert to bf16 (UNSCALED - ints exact in bf16), ds_write_b128 swizzled.
    const int srb = tid >> 2;
    const int skb = (tid & 3) * 8;
    const int* bsrc = Q + (size_t)(col0 + srb) * IN_F + skb;
    const int bslot = (((tid & 3) ^ (srb & 3)) * 8);
    int4v b0, b1;
    auto writeB = [&](int buf) {
        Pack8 v0;
        #pragma unroll
        for (int i = 0; i < 4; ++i) {
            v0.h[i]     = __float2bfloat16((float)b0[i]);
            v0.h[4 + i] = __float2bfloat16((float)b1[i]);
        }
        *(bf16x8*)&sB[buf][srb * BK + bslot] = v0.v;
    };

    // Prologue: A tiles 0,1 in flight; B tile 0 written; B regs t=1 in flight.
    b0 = *(const int4v*)(bsrc + 0);
    b1 = *(const int4v*)(bsrc + 4);
    issueA(0, 0);
    issueA(1, BK);
    writeB(0);                         // compiler waits only the B regs
    b0 = *(const int4v*)(bsrc + BK + 0);
    b1 = *(const int4v*)(bsrc + BK + 4);
    asm volatile("s_waitcnt vmcnt(4) lgkmcnt(0)" ::: "memory");  // A(0) done
    __builtin_amdgcn_s_barrier();

    for (int t = 0; t < NT; ++t) {
        const int cur  = t % 3;        // A buffer being consumed
        const int bcur = t & 1;

        if (t + 2 < NT) issueA((t + 2) % 3, (t + 2) * BK);   // 2 vmem

        // Fragment reads (swizzled slots).
        bf16x8 fa[4], fb[2];
        #pragma unroll
        for (int mi = 0; mi < 4; ++mi) {
            const int row = wm + mi * 16 + fr;
            fa[mi] = *(const bf16x8*)&sA[cur][row * BK + ((fc ^ (row & 3)) * 8)];
        }
        #pragma unroll
        for (int ni = 0; ni < 2; ++ni) {
            const int row = wn + ni * 16 + fr;
            fb[ni] = *(const bf16x8*)&sB[bcur][row * BK + ((fc ^ (row & 3)) * 8)];
        }

        if (t + 1 < NT) writeB(bcur ^ 1);          // regs from last iter
        if (t + 2 < NT) {                          // 2 vmem
            b0 = *(const int4v*)(bsrc + (t + 2) * BK + 0);
            b1 = *(const int4v*)(bsrc + (t + 2) * BK + 4);
        }

        #pragma unroll
        for (int mi = 0; mi < 4; ++mi)
            #pragma unroll
            for (int ni = 0; ni < 2; ++ni)
                acc[mi][ni] = __builtin_amdgcn_mfma_f32_16x16x32_bf16(
                    fa[mi], fb[ni], acc[mi][ni], 0, 0, 0);

        // Publish: A(t+1) + B ds_write must be done; keep A(t+2)+Bregs(t+2).
        if (t + 2 < NT)
            asm volatile("s_waitcnt vmcnt(4) lgkmcnt(0)" ::: "memory");
        else
            asm volatile("s_waitcnt vmcnt(0) lgkmcnt(0)" ::: "memory");
        __builtin_amdgcn_s_barrier();
    }

    // Apply row scale to the accumulator (deferred from dequant).
    const int ec = fr;                 // C/D col=lane&15
    #pragma unroll
    for (int ni = 0; ni < 2; ++ni) {
        const float sc = scale[col0 + wn + ni * 16 + ec];
        #pragma unroll
        for (int mi = 0; mi < 4; ++mi)
            #pragma unroll
            for (int r = 0; r < 4; ++r)
                acc[mi][ni][r] *= sc;
    }

    // Outlier deltas -> registers.
    if (tid == 0) lcount = 0;
    __syncthreads();
    for (int c = tid; c < NOUT; c += 256) {
        const int p = tabi[c];
        const int r = p >> 16;
        if (r >= col0 && r < col0 + BN) {
            const int pos = atomicAdd(&lcount, 1);
            if (pos < 256) { list[pos] = p; ldel[pos] = tabf[c]; }
        }
    }
    __syncthreads();
    const int nm = lcount < 256 ? lcount : 256;
    for (int u = 0; u < nm; ++u) {
        const int p    = list[u];
        const int ocl  = (p >> 16) - col0;   // 0..63
        const int ocol = p & 0xFFFF;
        if (((ocl >> 5) == (wave & 1)) && ((lane & 15) == (ocl & 15))) {
            const int ni = (ocl >> 4) & 1;
            const float d = ldel[u];
            #pragma unroll
            for (int mi = 0; mi < 4; ++mi)
                #pragma unroll
                for (int r2 = 0; r2 < 4; ++r2) {
                    const int grow = row0 + wm + mi * 16 + fc * 4 + r2;
                    acc[mi][ni][r2] += d * __bfloat162float(Xb[(size_t)grow * IN_F + ocol]);
                }
        }
    }

    // Epilogue: bias + store. C/D: col=lane&15, row=(lane>>4)*4+reg.
    const int er = fc * 4;
    #pragma unroll
    for (int ni = 0; ni < 2; ++ni) {
        const int gcol = col0 + wn + ni * 16 + ec;
        const float bv = bias[gcol];
        #pragma unroll
        for (int mi = 0; mi < 4; ++mi) {
            const int grow = row0 + wm + mi * 16 + er;
            #pragma unroll
            for (int r = 0; r < 4; ++r)
                out[(size_t)(grow + r) * OUT_F + gcol] = acc[mi][ni][r] + bv;
        }
    }
}

extern "C" void kernel_launch(void* const* d_in, const int* in_sizes, int n_in,
                              void* d_out, int out_size, void* d_ws, size_t ws_size,
                              hipStream_t stream) {
    const float* x    = (const float*)d_in[0];
    const int*   q    = (const int*)d_in[1];
    const float* qs   = (const float*)d_in[2];
    const float* qo   = (const float*)d_in[3];
    const int*   qi   = (const int*)d_in[4];
    const float* bias = (const float*)d_in[5];
    float* out = (float*)d_out;

    __hip_bfloat16* Xb = (__hip_bfloat16*)d_ws;
    int*   tabi = (int*)((char*)d_ws + WS_TAB_I);
    float* tabf = (float*)((char*)d_ws + WS_TAB_F);
    int*   hkey = (int*)((char*)d_ws + WS_HKEY);
    int*   hval = (int*)((char*)d_ws + WS_HVAL);

    prep_x<<<dim3(SEQ * IN_F / 2048), 256, 0, stream>>>(x, Xb);
    hipMemsetAsync((void*)hkey, 0xFF, (size_t)HSLOTS * 8, stream);  // hkey+hval = -1
    prep_hins<<<dim3(NOUT / 256), 256, 0, stream>>>(qi, hkey, hval);
    prep_tab<<<dim3(NOUT / 256), 256, 0, stream>>>(qi, qo, q, qs, hkey, hval, tabi, tabf);
    qgemm4<<<dim3(NWG), 256, 0, stream>>>(Xb, q, qs, bias, tabi, tabf, out);
}

// Round 6
// 183.201 us; speedup vs baseline: 1.1158x; 1.1158x over previous
//
#include <hip/hip_runtime.h>
#include <hip/hip_bf16.h>

#define IN_F  4096
#define OUT_F 11008
#define SEQ   512
#define NOUT  4096

#define BM 64
#define BN 64
#define BK 64
#define NT   (IN_F / BK)        // 64 K-phases
#define NBLK (OUT_F / BN)       // 172
#define MBLK (SEQ / BM)         // 8
#define NWG  (NBLK * MBLK)      // 1376 = 8 * 172 -> bijective XCD swizzle

#define HSLOTS 8192             // dedup hash table (load factor 0.5)

// ws layout: [0,4MB) X as bf16; dedup'd outlier table; hash table
#define WS_TAB_I ((size_t)SEQ * IN_F * 2)
#define WS_TAB_F (WS_TAB_I + (size_t)NOUT * 4)
#define WS_HKEY  (WS_TAB_F + (size_t)NOUT * 4)
#define WS_HVAL  (WS_HKEY + (size_t)HSLOTS * 4)

typedef __attribute__((ext_vector_type(8))) short bf16x8;
typedef __attribute__((ext_vector_type(4))) float f32x4;
typedef __attribute__((ext_vector_type(4))) int   int4v;
typedef __attribute__((ext_vector_type(4))) float float4v;

union Pack8 { bf16x8 v; __hip_bfloat16 h[8]; };

__device__ __forceinline__ unsigned hslot(int key) {
    return ((unsigned)key * 2654435761u) & (HSLOTS - 1);
}

// ---- prep 1: X fp32 -> bf16 (vectorized) ----
__global__ __launch_bounds__(256) void prep_x(const float* __restrict__ X,
                                              __hip_bfloat16* __restrict__ Xb) {
    const int i = (blockIdx.x * 256 + threadIdx.x) * 8;
    float4v x0 = *(const float4v*)(X + i);
    float4v x1 = *(const float4v*)(X + i + 4);
    Pack8 p;
    #pragma unroll
    for (int j = 0; j < 4; ++j) {
        p.h[j]     = __float2bfloat16(x0[j]);
        p.h[4 + j] = __float2bfloat16(x1[j]);
    }
    *(bf16x8*)(Xb + i) = p.v;
}

// ---- prep 2a: insert outliers, last-wins via atomicMax on entry index ----
__global__ __launch_bounds__(256) void prep_hins(const int* __restrict__ oidx,
                                                 int* __restrict__ hkey,
                                                 int* __restrict__ hval) {
    const int j = blockIdx.x * 256 + threadIdx.x;
    const int key = oidx[2 * j] * IN_F + oidx[2 * j + 1];
    unsigned s = hslot(key);
    while (true) {
        const int prev = atomicCAS(&hkey[s], -1, key);
        if (prev == -1 || prev == key) break;
        s = (s + 1) & (HSLOTS - 1);
    }
    atomicMax(&hval[s], j);
}

// ---- prep 2b: resolve dups + delta table (delta vs EXACT q*scale; GEMM
// contributes scale[o] * (exact int q) * bf16(x)) ----
__global__ __launch_bounds__(256) void prep_tab(
    const int* __restrict__ oidx, const float* __restrict__ outv,
    const int* __restrict__ Q, const float* __restrict__ scale,
    const int* __restrict__ hkey, const int* __restrict__ hval,
    int* __restrict__ tabi, float* __restrict__ tabf) {
    const int j = blockIdx.x * 256 + threadIdx.x;
    const int r = oidx[2 * j], c = oidx[2 * j + 1];
    const int key = r * IN_F + c;
    unsigned s = hslot(key);
    while (hkey[s] != key) s = (s + 1) & (HSLOTS - 1);
    if (hval[s] != j) { tabi[j] = -1; tabf[j] = 0.f; return; }   // later dup wins
    tabi[j] = (r << 16) | c;
    tabf[j] = outv[j] - (float)Q[(size_t)r * IN_F + c] * scale[r];
}

// ---- main: R4's proven BK=64 pipeline, BM=64 for 2x grid/occupancy.
// Unscaled int-as-bf16 GEMM; A via gload_lds (src XOR-preswizzled), B reg-
// staged 2-ahead; counted vmcnt(4); scale+outliers+bias in epilogue.
__global__ __launch_bounds__(256) void qgemm5(
    const __hip_bfloat16* __restrict__ Xb,
    const int*   __restrict__ Q,
    const float* __restrict__ scale,
    const float* __restrict__ bias,
    const int*   __restrict__ tabi,
    const float* __restrict__ tabf,
    float* __restrict__ out)
{
    __shared__ __hip_bfloat16 sA[2][BM * BK];   // 16 KB, chunk-swizzled
    __shared__ __hip_bfloat16 sB[2][BN * BK];   // 16 KB, chunk-swizzled
    __shared__ int   list[256];
    __shared__ float ldel[256];
    __shared__ int   lcount;

    const int tid  = threadIdx.x;
    const int wave = tid >> 6;
    const int lane = tid & 63;

    // XCD swizzle: XCD k owns 172 consecutive tiles; 8 consecutive tiles
    // share one Q panel (1MB -> L2 reuse).
    const int lin = blockIdx.x;
    const int t0  = (lin & 7) * (NWG / 8) + (lin >> 3);
    const int col0 = (t0 >> 3) * BN;
    const int row0 = (t0 & 7) * BM;

    const int wm = (wave >> 1) * 32;   // wave sub-tile: 32x32
    const int wn = (wave & 1) * 32;
    const int fr = lane & 15;          // fragment row within 16
    const int fc = lane >> 4;          // k-chunk group 0..3

    f32x4 acc[2][2] = {};

    // A staging: 8KB/tile via 2 gload_lds/thread. Call i covers rows
    // wave*16+i*8..+7; lane l -> row_off l>>3, chunk slot l&7 (16B chunks).
    // Source chunk XOR-preswizzled: LDS slot s of row r holds logical s^(r&7).
    const int arow = wave * 16 + (lane >> 3);
    const __hip_bfloat16* asrc =
        Xb + (size_t)(row0 + arow) * IN_F + (((lane & 7) ^ (lane >> 3)) * 8);
    auto issueA = [&](int buf, int k0) {
        #pragma unroll
        for (int i = 0; i < 2; ++i)
            __builtin_amdgcn_global_load_lds(
                (const __attribute__((address_space(1))) void*)(asrc + (size_t)i * 8 * IN_F + k0),
                (__attribute__((address_space(3))) void*)&sA[buf][(wave * 2 + i) * 8 * BK],
                16, 0, 0);
    };

    // B staging: thread covers Q row srb (4 thr/row), 16 ints at (tid&3)*16;
    // convert to bf16 (UNSCALED - ints exact), ds_write_b128 XOR-swizzled.
    const int srb = tid >> 2;
    const int skb = (tid & 3) * 16;
    const int* bsrc = Q + (size_t)(col0 + srb) * IN_F + skb;
    int4v b0, b1, b2, b3;
    auto writeB = [&](int buf) {
        Pack8 v0, v1;
        #pragma unroll
        for (int i = 0; i < 4; ++i) {
            v0.h[i]     = __float2bfloat16((float)b0[i]);
            v0.h[4 + i] = __float2bfloat16((float)b1[i]);
            v1.h[i]     = __float2bfloat16((float)b2[i]);
            v1.h[4 + i] = __float2bfloat16((float)b3[i]);
        }
        const int c0 = (tid & 3) * 2;
        const int s7 = srb & 7;
        *(bf16x8*)&sB[buf][srb * BK + ((c0 ^ s7) * 8)]       = v0.v;
        *(bf16x8*)&sB[buf][srb * BK + (((c0 + 1) ^ s7) * 8)] = v1.v;
    };

    // Prologue: tile0 staged; B regs for tile1 left in flight across barrier.
    b0 = *(const int4v*)(bsrc + 0);
    b1 = *(const int4v*)(bsrc + 4);
    b2 = *(const int4v*)(bsrc + 8);
    b3 = *(const int4v*)(bsrc + 12);
    issueA(0, 0);
    writeB(0);                          // compiler waits only b(0) regs
    b0 = *(const int4v*)(bsrc + BK + 0);
    b1 = *(const int4v*)(bsrc + BK + 4);
    b2 = *(const int4v*)(bsrc + BK + 8);
    b3 = *(const int4v*)(bsrc + BK + 12);
    asm volatile("s_waitcnt vmcnt(4) lgkmcnt(0)" ::: "memory");  // drain A(0), keep b(1)
    __builtin_amdgcn_s_barrier();

    for (int t = 0; t < NT; ++t) {
        const int cur = t & 1;
        if (t + 1 < NT) issueA(cur ^ 1, (t + 1) * BK);   // 2 vmem

        // Fragment reads (swizzled slots; conflict-free, 8-slot spread).
        bf16x8 fa[2][2], fb[2][2];
        #pragma unroll
        for (int kk = 0; kk < 2; ++kk) {
            #pragma unroll
            for (int mi = 0; mi < 2; ++mi) {
                const int row = wm + mi * 16 + fr;
                fa[kk][mi] = *(const bf16x8*)&sA[cur][row * BK + (((kk * 4 + fc) ^ (row & 7)) * 8)];
            }
            #pragma unroll
            for (int ni = 0; ni < 2; ++ni) {
                const int row = wn + ni * 16 + fr;
                fb[kk][ni] = *(const bf16x8*)&sB[cur][row * BK + (((kk * 4 + fc) ^ (row & 7)) * 8)];
            }
        }
        if (t + 1 < NT) writeB(cur ^ 1);           // waits b(t+1) via vmcnt(2)
        if (t + 2 < NT) {                          // 4 vmem: b(t+2)
            b0 = *(const int4v*)(bsrc + (t + 2) * BK + 0);
            b1 = *(const int4v*)(bsrc + (t + 2) * BK + 4);
            b2 = *(const int4v*)(bsrc + (t + 2) * BK + 8);
            b3 = *(const int4v*)(bsrc + (t + 2) * BK + 12);
        }
        #pragma unroll
        for (int kk = 0; kk < 2; ++kk)
            #pragma unroll
            for (int mi = 0; mi < 2; ++mi)
                #pragma unroll
                for (int ni = 0; ni < 2; ++ni)
                    acc[mi][ni] = __builtin_amdgcn_mfma_f32_16x16x32_bf16(
                        fa[kk][mi], fb[kk][ni], acc[mi][ni], 0, 0, 0);

        // Publish: drain A(t+1)+B ds_write; keep b(t+2) regs (4) in flight.
        if (t + 2 < NT)
            asm volatile("s_waitcnt vmcnt(4) lgkmcnt(0)" ::: "memory");
        else
            asm volatile("s_waitcnt vmcnt(0) lgkmcnt(0)" ::: "memory");
        __builtin_amdgcn_s_barrier();
    }

    // Deferred row scale on the accumulator.
    const int ec = fr;                 // C/D col=lane&15
    #pragma unroll
    for (int ni = 0; ni < 2; ++ni) {
        const float sc = scale[col0 + wn + ni * 16 + ec];
        #pragma unroll
        for (int mi = 0; mi < 2; ++mi)
            #pragma unroll
            for (int r = 0; r < 4; ++r)
                acc[mi][ni][r] *= sc;
    }

    // Outlier deltas -> registers (block owns its out tile exclusively).
    if (tid == 0) lcount = 0;
    __syncthreads();
    for (int c = tid; c < NOUT; c += 256) {
        const int p = tabi[c];
        const int r = p >> 16;
        if (r >= col0 && r < col0 + BN) {
            const int pos = atomicAdd(&lcount, 1);
            if (pos < 256) { list[pos] = p; ldel[pos] = tabf[c]; }
        }
    }
    __syncthreads();
    const int nm = lcount < 256 ? lcount : 256;
    for (int u = 0; u < nm; ++u) {
        const int p    = list[u];
        const int ocl  = (p >> 16) - col0;   // 0..63
        const int ocol = p & 0xFFFF;
        if (((ocl >> 5) == (wave & 1)) && ((lane & 15) == (ocl & 15))) {
            const int ni = (ocl >> 4) & 1;
            const float d = ldel[u];
            #pragma unroll
            for (int mi = 0; mi < 2; ++mi)
                #pragma unroll
                for (int r2 = 0; r2 < 4; ++r2) {
                    const int grow = row0 + wm + mi * 16 + fc * 4 + r2;
                    acc[mi][ni][r2] += d * __bfloat162float(Xb[(size_t)grow * IN_F + ocol]);
                }
        }
    }

    // Epilogue: bias + store. C/D: col=lane&15, row=(lane>>4)*4+reg.
    const int er = fc * 4;
    #pragma unroll
    for (int ni = 0; ni < 2; ++ni) {
        const int gcol = col0 + wn + ni * 16 + ec;
        const float bv = bias[gcol];
        #pragma unroll
        for (int mi = 0; mi < 2; ++mi) {
            const int grow = row0 + wm + mi * 16 + er;
            #pragma unroll
            for (int r = 0; r < 4; ++r)
                out[(size_t)(grow + r) * OUT_F + gcol] = acc[mi][ni][r] + bv;
        }
    }
}

extern "C" void kernel_launch(void* const* d_in, const int* in_sizes, int n_in,
                              void* d_out, int out_size, void* d_ws, size_t ws_size,
                              hipStream_t stream) {
    const float* x    = (const float*)d_in[0];
    const int*   q    = (const int*)d_in[1];
    const float* qs   = (const float*)d_in[2];
    const float* qo   = (const float*)d_in[3];
    const int*   qi   = (const int*)d_in[4];
    const float* bias = (const float*)d_in[5];
    float* out = (float*)d_out;

    __hip_bfloat16* Xb = (__hip_bfloat16*)d_ws;
    int*   tabi = (int*)((char*)d_ws + WS_TAB_I);
    float* tabf = (float*)((char*)d_ws + WS_TAB_F);
    int*   hkey = (int*)((char*)d_ws + WS_HKEY);
    int*   hval = (int*)((char*)d_ws + WS_HVAL);

    prep_x<<<dim3(SEQ * IN_F / 2048), 256, 0, stream>>>(x, Xb);
    hipMemsetAsync((void*)hkey, 0xFF, (size_t)HSLOTS * 8, stream);  // hkey+hval = -1
    prep_hins<<<dim3(NOUT / 256), 256, 0, stream>>>(qi, hkey, hval);
    prep_tab<<<dim3(NOUT / 256), 256, 0, stream>>>(qi, qo, q, qs, hkey, hval, tabi, tabf);
    qgemm5<<<dim3(NWG), 256, 0, stream>>>(Xb, q, qs, bias, tabi, tabf, out);
}

// Round 7
// 175.100 us; speedup vs baseline: 1.1674x; 1.0463x over previous
//
#include <hip/hip_runtime.h>
#include <hip/hip_bf16.h>

#define IN_F  4096
#define OUT_F 11008
#define SEQ   512
#define NOUT  4096

#define BM 128
#define BN 64
#define BK 64
#define NT   (IN_F / BK)        // 64 K-phases
#define NBLK (OUT_F / BN)       // 172
#define MBLK (SEQ / BM)         // 4
#define NWG  (NBLK * MBLK)      // 688 = 8 * 86 -> bijective XCD swizzle

#define HSLOTS 8192             // dedup hash table (load factor 0.5)

// ws layout: Xb (4MB) | tabi | tabf | hkey | hval | Qb (90MB, big path only)
#define WS_TAB_I ((size_t)SEQ * IN_F * 2)
#define WS_TAB_F (WS_TAB_I + (size_t)NOUT * 4)
#define WS_HKEY  (WS_TAB_F + (size_t)NOUT * 4)
#define WS_HVAL  (WS_HKEY + (size_t)HSLOTS * 4)
#define WS_QB    (WS_HVAL + (size_t)HSLOTS * 4)
#define WS_NEED  (WS_QB + (size_t)OUT_F * IN_F * 2)

typedef __attribute__((ext_vector_type(8))) short bf16x8;
typedef __attribute__((ext_vector_type(4))) float f32x4;
typedef __attribute__((ext_vector_type(4))) int   int4v;
typedef __attribute__((ext_vector_type(4))) float float4v;

union Pack8 { bf16x8 v; __hip_bfloat16 h[8]; };

__device__ __forceinline__ unsigned hslot(int key) {
    return ((unsigned)key * 2654435761u) & (HSLOTS - 1);
}

// ---- prep 1: X fp32 -> bf16 (vectorized) ----
__global__ __launch_bounds__(256) void prep_x(const float* __restrict__ X,
                                              __hip_bfloat16* __restrict__ Xb) {
    const int i = (blockIdx.x * 256 + threadIdx.x) * 8;
    float4v x0 = *(const float4v*)(X + i);
    float4v x1 = *(const float4v*)(X + i + 4);
    Pack8 p;
    #pragma unroll
    for (int j = 0; j < 4; ++j) {
        p.h[j]     = __float2bfloat16(x0[j]);
        p.h[4 + j] = __float2bfloat16(x1[j]);
    }
    *(bf16x8*)(Xb + i) = p.v;
}

// ---- prep 1b: Q int32 -> bf16 UNSCALED (ints <=128 exact in bf16) ----
__global__ __launch_bounds__(256) void prep_q(const int* __restrict__ Q,
                                              __hip_bfloat16* __restrict__ Qb) {
    const size_t i = ((size_t)blockIdx.x * 256 + threadIdx.x) * 8;
    int4v q0 = *(const int4v*)(Q + i);
    int4v q1 = *(const int4v*)(Q + i + 4);
    Pack8 p;
    #pragma unroll
    for (int j = 0; j < 4; ++j) {
        p.h[j]     = __float2bfloat16((float)q0[j]);
        p.h[4 + j] = __float2bfloat16((float)q1[j]);
    }
    *(bf16x8*)(Qb + i) = p.v;
}

// ---- prep 2a: insert outliers, last-wins via atomicMax on entry index ----
__global__ __launch_bounds__(256) void prep_hins(const int* __restrict__ oidx,
                                                 int* __restrict__ hkey,
                                                 int* __restrict__ hval) {
    const int j = blockIdx.x * 256 + threadIdx.x;
    const int key = oidx[2 * j] * IN_F + oidx[2 * j + 1];
    unsigned s = hslot(key);
    while (true) {
        const int prev = atomicCAS(&hkey[s], -1, key);
        if (prev == -1 || prev == key) break;
        s = (s + 1) & (HSLOTS - 1);
    }
    atomicMax(&hval[s], j);
}

// ---- prep 2b: resolve dups + delta table (delta vs EXACT q*scale) ----
__global__ __launch_bounds__(256) void prep_tab(
    const int* __restrict__ oidx, const float* __restrict__ outv,
    const int* __restrict__ Q, const float* __restrict__ scale,
    const int* __restrict__ hkey, const int* __restrict__ hval,
    int* __restrict__ tabi, float* __restrict__ tabf) {
    const int j = blockIdx.x * 256 + threadIdx.x;
    const int r = oidx[2 * j], c = oidx[2 * j + 1];
    const int key = r * IN_F + c;
    unsigned s = hslot(key);
    while (hkey[s] != key) s = (s + 1) & (HSLOTS - 1);
    if (hval[s] != j) { tabi[j] = -1; tabf[j] = 0.f; return; }   // later dup wins
    tabi[j] = (r << 16) | c;
    tabf[j] = outv[j] - (float)Q[(size_t)r * IN_F + c] * scale[r];
}

// ---- main (big-ws path): LEAN loop — both A and B staged via
// global_load_lds from bf16 (src XOR-preswizzled, conflict-free ds_reads),
// ZERO VALU in the K-loop. m97 structure. Scale/outliers/bias in epilogue.
__global__ __launch_bounds__(256) void qgemm6(
    const __hip_bfloat16* __restrict__ Xb,
    const __hip_bfloat16* __restrict__ Qb,
    const float* __restrict__ scale,
    const float* __restrict__ bias,
    const int*   __restrict__ tabi,
    const float* __restrict__ tabf,
    float* __restrict__ out)
{
    __shared__ __hip_bfloat16 sA[2][BM * BK];   // 32 KB
    __shared__ __hip_bfloat16 sB[2][BN * BK];   // 16 KB
    __shared__ int   list[256];
    __shared__ float ldel[256];
    __shared__ int   lcount;

    const int tid  = threadIdx.x;
    const int wave = tid >> 6;
    const int lane = tid & 63;

    // XCD swizzle; 4 consecutive tiles share one Qb panel (0.5MB -> L2 reuse).
    const int lin = blockIdx.x;
    const int t0  = (lin & 7) * (NWG / 8) + (lin >> 3);
    const int col0 = (t0 >> 2) * BN;
    const int row0 = (t0 & 3) * BM;

    const int wm = (wave >> 1) * 64;
    const int wn = (wave & 1) * 32;
    const int fr = lane & 15;          // fragment row within 16
    const int fc = lane >> 4;          // k-chunk group 0..3

    f32x4 acc[4][2] = {};

    // A: 16KB/tile, 4 gload_lds/thread. Issue i covers rows wave*32+i*8..+7.
    // Source chunk XOR-preswizzled: LDS slot s of row r holds logical s^(r&7).
    const __hip_bfloat16* asrc =
        Xb + (size_t)(row0 + wave * 32 + (lane >> 3)) * IN_F
           + (((lane & 7) ^ (lane >> 3)) * 8);
    // B: 8KB/tile, 2 gload_lds/thread. Issue i covers rows i*32+wave*8..+7.
    const __hip_bfloat16* bsrc =
        Qb + (size_t)(col0 + wave * 8 + (lane >> 3)) * IN_F
           + (((lane & 7) ^ (lane >> 3)) * 8);

    auto issueAB = [&](int buf, int k0) {
        #pragma unroll
        for (int i = 0; i < 4; ++i)
            __builtin_amdgcn_global_load_lds(
                (const __attribute__((address_space(1))) void*)(asrc + (size_t)i * 8 * IN_F + k0),
                (__attribute__((address_space(3))) void*)&sA[buf][(wave * 32 + i * 8) * BK],
                16, 0, 0);
        #pragma unroll
        for (int i = 0; i < 2; ++i)
            __builtin_amdgcn_global_load_lds(
                (const __attribute__((address_space(1))) void*)(bsrc + (size_t)i * 32 * IN_F + k0),
                (__attribute__((address_space(3))) void*)&sB[buf][(i * 32 + wave * 8) * BK],
                16, 0, 0);
    };

    // Prologue.
    issueAB(0, 0);
    asm volatile("s_waitcnt vmcnt(0) lgkmcnt(0)" ::: "memory");
    __builtin_amdgcn_s_barrier();

    for (int t = 0; t < NT; ++t) {
        const int cur = t & 1;
        if (t + 1 < NT) issueAB(cur ^ 1, (t + 1) * BK);   // 6 vmem, prefetch t+1

        bf16x8 fa[2][4], fb[2][2];
        #pragma unroll
        for (int kk = 0; kk < 2; ++kk) {
            #pragma unroll
            for (int mi = 0; mi < 4; ++mi) {
                const int row = wm + mi * 16 + fr;
                fa[kk][mi] = *(const bf16x8*)&sA[cur][row * BK + (((kk * 4 + fc) ^ (row & 7)) * 8)];
            }
            #pragma unroll
            for (int ni = 0; ni < 2; ++ni) {
                const int row = wn + ni * 16 + fr;
                fb[kk][ni] = *(const bf16x8*)&sB[cur][row * BK + (((kk * 4 + fc) ^ (row & 7)) * 8)];
            }
        }
        #pragma unroll
        for (int kk = 0; kk < 2; ++kk)
            #pragma unroll
            for (int mi = 0; mi < 4; ++mi)
                #pragma unroll
                for (int ni = 0; ni < 2; ++ni)
                    acc[mi][ni] = __builtin_amdgcn_mfma_f32_16x16x32_bf16(
                        fa[kk][mi], fb[kk][ni], acc[mi][ni], 0, 0, 0);

        asm volatile("s_waitcnt vmcnt(0) lgkmcnt(0)" ::: "memory");
        __builtin_amdgcn_s_barrier();
    }

    // Deferred row scale.
    const int ec = fr;
    #pragma unroll
    for (int ni = 0; ni < 2; ++ni) {
        const float sc = scale[col0 + wn + ni * 16 + ec];
        #pragma unroll
        for (int mi = 0; mi < 4; ++mi)
            #pragma unroll
            for (int r = 0; r < 4; ++r)
                acc[mi][ni][r] *= sc;
    }

    // Outlier deltas -> registers.
    if (tid == 0) lcount = 0;
    __syncthreads();
    for (int c = tid; c < NOUT; c += 256) {
        const int p = tabi[c];
        const int r = p >> 16;
        if (r >= col0 && r < col0 + BN) {
            const int pos = atomicAdd(&lcount, 1);
            if (pos < 256) { list[pos] = p; ldel[pos] = tabf[c]; }
        }
    }
    __syncthreads();
    const int nm = lcount < 256 ? lcount : 256;
    for (int u = 0; u < nm; ++u) {
        const int p    = list[u];
        const int ocl  = (p >> 16) - col0;   // 0..63
        const int ocol = p & 0xFFFF;
        if (((ocl >> 5) == (wave & 1)) && ((lane & 15) == (ocl & 15))) {
            const int ni = (ocl >> 4) & 1;
            const float d = ldel[u];
            #pragma unroll
            for (int mi = 0; mi < 4; ++mi)
                #pragma unroll
                for (int r2 = 0; r2 < 4; ++r2) {
                    const int grow = row0 + wm + mi * 16 + fc * 4 + r2;
                    acc[mi][ni][r2] += d * __bfloat162float(Xb[(size_t)grow * IN_F + ocol]);
                }
        }
    }

    // Bias + store. C/D: col=lane&15, row=(lane>>4)*4+reg.
    const int er = fc * 4;
    #pragma unroll
    for (int ni = 0; ni < 2; ++ni) {
        const int gcol = col0 + wn + ni * 16 + ec;
        const float bv = bias[gcol];
        #pragma unroll
        for (int mi = 0; mi < 4; ++mi) {
            const int grow = row0 + wm + mi * 16 + er;
            #pragma unroll
            for (int r = 0; r < 4; ++r)
                out[(size_t)(grow + r) * OUT_F + gcol] = acc[mi][ni][r] + bv;
        }
    }
}

// ---- fallback (small ws): R4's proven qgemm3 (int32 B reg-staged) ----
__global__ __launch_bounds__(256) void qgemm3_fb(
    const __hip_bfloat16* __restrict__ Xb,
    const int*   __restrict__ Q,
    const float* __restrict__ scale,
    const float* __restrict__ bias,
    const int*   __restrict__ tabi,
    const float* __restrict__ tabf,
    float* __restrict__ out)
{
    __shared__ __hip_bfloat16 sA[2][BM * BK];
    __shared__ __hip_bfloat16 sB[2][BN * BK];
    __shared__ int   list[256];
    __shared__ float ldel[256];
    __shared__ int   lcount;

    const int tid  = threadIdx.x;
    const int wave = tid >> 6;
    const int lane = tid & 63;

    const int lin = blockIdx.x;
    const int t0  = (lin & 7) * (NWG / 8) + (lin >> 3);
    const int col0 = (t0 >> 2) * BN;
    const int row0 = (t0 & 3) * BM;

    const int wm = (wave >> 1) * 64;
    const int wn = (wave & 1) * 32;
    const int fr = lane & 15;
    const int fc = lane >> 4;

    f32x4 acc[4][2] = {};

    const int arow = wave * 32 + (lane >> 3);
    const __hip_bfloat16* asrc =
        Xb + (size_t)(row0 + arow) * IN_F + (((lane & 7) ^ (lane >> 3)) * 8);
    auto issueA = [&](int buf, int k0) {
        #pragma unroll
        for (int i = 0; i < 4; ++i)
            __builtin_amdgcn_global_load_lds(
                (const __attribute__((address_space(1))) void*)(asrc + (size_t)i * 8 * IN_F + k0),
                (__attribute__((address_space(3))) void*)&sA[buf][(wave * 4 + i) * 8 * BK],
                16, 0, 0);
    };

    const int srb = tid >> 2;
    const int skb = (tid & 3) * 16;
    const int* bsrc = Q + (size_t)(col0 + srb) * IN_F + skb;
    int4v b0, b1, b2, b3;
    auto writeB = [&](int buf) {
        Pack8 v0, v1;
        #pragma unroll
        for (int i = 0; i < 4; ++i) {
            v0.h[i]     = __float2bfloat16((float)b0[i]);
            v0.h[4 + i] = __float2bfloat16((float)b1[i]);
            v1.h[i]     = __float2bfloat16((float)b2[i]);
            v1.h[4 + i] = __float2bfloat16((float)b3[i]);
        }
        const int c0 = (tid & 3) * 2;
        const int s7 = srb & 7;
        *(bf16x8*)&sB[buf][srb * BK + ((c0 ^ s7) * 8)]       = v0.v;
        *(bf16x8*)&sB[buf][srb * BK + (((c0 + 1) ^ s7) * 8)] = v1.v;
    };

    b0 = *(const int4v*)(bsrc + 0);
    b1 = *(const int4v*)(bsrc + 4);
    b2 = *(const int4v*)(bsrc + 8);
    b3 = *(const int4v*)(bsrc + 12);
    issueA(0, 0);
    writeB(0);
    b0 = *(const int4v*)(bsrc + BK + 0);
    b1 = *(const int4v*)(bsrc + BK + 4);
    b2 = *(const int4v*)(bsrc + BK + 8);
    b3 = *(const int4v*)(bsrc + BK + 12);
    asm volatile("s_waitcnt vmcnt(4) lgkmcnt(0)" ::: "memory");
    __builtin_amdgcn_s_barrier();

    for (int t = 0; t < NT; ++t) {
        const int cur = t & 1;
        if (t + 1 < NT) issueA(cur ^ 1, (t + 1) * BK);

        bf16x8 fa[2][4], fb[2][2];
        #pragma unroll
        for (int kk = 0; kk < 2; ++kk) {
            #pragma unroll
            for (int mi = 0; mi < 4; ++mi) {
                const int row = wm + mi * 16 + fr;
                fa[kk][mi] = *(const bf16x8*)&sA[cur][row * BK + (((kk * 4 + fc) ^ (row & 7)) * 8)];
            }
            #pragma unroll
            for (int ni = 0; ni < 2; ++ni) {
                const int row = wn + ni * 16 + fr;
                fb[kk][ni] = *(const bf16x8*)&sB[cur][row * BK + (((kk * 4 + fc) ^ (row & 7)) * 8)];
            }
        }
        if (t + 1 < NT) writeB(cur ^ 1);
        if (t + 2 < NT) {
            b0 = *(const int4v*)(bsrc + (t + 2) * BK + 0);
            b1 = *(const int4v*)(bsrc + (t + 2) * BK + 4);
            b2 = *(const int4v*)(bsrc + (t + 2) * BK + 8);
            b3 = *(const int4v*)(bsrc + (t + 2) * BK + 12);
        }
        #pragma unroll
        for (int kk = 0; kk < 2; ++kk)
            #pragma unroll
            for (int mi = 0; mi < 4; ++mi)
                #pragma unroll
                for (int ni = 0; ni < 2; ++ni)
                    acc[mi][ni] = __builtin_amdgcn_mfma_f32_16x16x32_bf16(
                        fa[kk][mi], fb[kk][ni], acc[mi][ni], 0, 0, 0);

        if (t + 2 < NT)
            asm volatile("s_waitcnt vmcnt(4) lgkmcnt(0)" ::: "memory");
        else
            asm volatile("s_waitcnt vmcnt(0) lgkmcnt(0)" ::: "memory");
        __builtin_amdgcn_s_barrier();
    }

    const int ec = fr;
    #pragma unroll
    for (int ni = 0; ni < 2; ++ni) {
        const float sc = scale[col0 + wn + ni * 16 + ec];
        #pragma unroll
        for (int mi = 0; mi < 4; ++mi)
            #pragma unroll
            for (int r = 0; r < 4; ++r)
                acc[mi][ni][r] *= sc;
    }

    if (tid == 0) lcount = 0;
    __syncthreads();
    for (int c = tid; c < NOUT; c += 256) {
        const int p = tabi[c];
        const int r = p >> 16;
        if (r >= col0 && r < col0 + BN) {
            const int pos = atomicAdd(&lcount, 1);
            if (pos < 256) { list[pos] = p; ldel[pos] = tabf[c]; }
        }
    }
    __syncthreads();
    const int nm = lcount < 256 ? lcount : 256;
    for (int u = 0; u < nm; ++u) {
        const int p    = list[u];
        const int ocl  = (p >> 16) - col0;
        const int ocol = p & 0xFFFF;
        if (((ocl >> 5) == (wave & 1)) && ((lane & 15) == (ocl & 15))) {
            const int ni = (ocl >> 4) & 1;
            const float d = ldel[u];
            #pragma unroll
            for (int mi = 0; mi < 4; ++mi)
                #pragma unroll
                for (int r2 = 0; r2 < 4; ++r2) {
                    const int grow = row0 + wm + mi * 16 + fc * 4 + r2;
                    acc[mi][ni][r2] += d * __bfloat162float(Xb[(size_t)grow * IN_F + ocol]);
                }
        }
    }

    const int er = fc * 4;
    #pragma unroll
    for (int ni = 0; ni < 2; ++ni) {
        const int gcol = col0 + wn + ni * 16 + ec;
        const float bv = bias[gcol];
        #pragma unroll
        for (int mi = 0; mi < 4; ++mi) {
            const int grow = row0 + wm + mi * 16 + er;
            #pragma unroll
            for (int r = 0; r < 4; ++r)
                out[(size_t)(grow + r) * OUT_F + gcol] = acc[mi][ni][r] + bv;
        }
    }
}

extern "C" void kernel_launch(void* const* d_in, const int* in_sizes, int n_in,
                              void* d_out, int out_size, void* d_ws, size_t ws_size,
                              hipStream_t stream) {
    const float* x    = (const float*)d_in[0];
    const int*   q    = (const int*)d_in[1];
    const float* qs   = (const float*)d_in[2];
    const float* qo   = (const float*)d_in[3];
    const int*   qi   = (const int*)d_in[4];
    const float* bias = (const float*)d_in[5];
    float* out = (float*)d_out;

    __hip_bfloat16* Xb = (__hip_bfloat16*)d_ws;
    int*   tabi = (int*)((char*)d_ws + WS_TAB_I);
    float* tabf = (float*)((char*)d_ws + WS_TAB_F);
    int*   hkey = (int*)((char*)d_ws + WS_HKEY);
    int*   hval = (int*)((char*)d_ws + WS_HVAL);
    __hip_bfloat16* Qb = (__hip_bfloat16*)((char*)d_ws + WS_QB);

    prep_x<<<dim3(SEQ * IN_F / 2048), 256, 0, stream>>>(x, Xb);
    hipMemsetAsync((void*)hkey, 0xFF, (size_t)HSLOTS * 8, stream);  // hkey+hval = -1
    prep_hins<<<dim3(NOUT / 256), 256, 0, stream>>>(qi, hkey, hval);
    prep_tab<<<dim3(NOUT / 256), 256, 0, stream>>>(qi, qo, q, qs, hkey, hval, tabi, tabf);

    if (ws_size >= WS_NEED) {
        prep_q<<<dim3((OUT_F * IN_F) / 2048), 256, 0, stream>>>(q, Qb);
        qgemm6<<<dim3(NWG), 256, 0, stream>>>(Xb, Qb, qs, bias, tabi, tabf, out);
    } else {
        qgemm3_fb<<<dim3(NWG), 256, 0, stream>>>(Xb, q, qs, bias, tabi, tabf, out);
    }
}